// Round 5
// baseline (51058.966 us; speedup 1.0000x reference)
//
#include <hip/hip_runtime.h>
#include <cmath>

#define NN   68     // nodes
#define KW   4      // K-split ways
#define CH   20     // padded chunk floats per lane (5 quads; 68 = 4*17, pad to 4*20)
#define NPAD 80     // KW*CH
#define NT   272    // NN*KW threads, 5 waves

// quad_perm DPP: xor1 = [1,0,3,2] = 0xB1, xor2 = [2,3,0,1] = 0x4E
__device__ __forceinline__ float dpp_xor1(float x) {
    return __int_as_float(__builtin_amdgcn_mov_dpp(__float_as_int(x), 0xB1, 0xF, 0xF, true));
}
__device__ __forceinline__ float dpp_xor2(float x) {
    return __int_as_float(__builtin_amdgcn_mov_dpp(__float_as_int(x), 0x4E, 0xF, 0xF, true));
}

#if __has_builtin(__builtin_amdgcn_exp2f)
#define FAST_EXP2(x) __builtin_amdgcn_exp2f(x)
#else
#define FAST_EXP2(x) exp2f(x)
#endif
#define FAST_RCP(x) __builtin_amdgcn_rcpf(x)

#define PIN4(q) asm volatile("" : "+v"(q.x), "+v"(q.y), "+v"(q.z), "+v"(q.w))

#define MAC4(c, e)                    \
    a0 = fmaf(c.x, e.x, a0);          \
    a1 = fmaf(c.y, e.y, a1);          \
    a2 = fmaf(c.z, e.z, a2);          \
    a3 = fmaf(c.w, e.w, a3);

__global__ __launch_bounds__(NT, 1)
void nmm_kernel(const float* __restrict__ params,
                const float* __restrict__ Cjk,
                const float* __restrict__ y0,
                float* __restrict__ out,
                const int num_steps)
{
    const int tid = threadIdx.x;
    const int j   = tid >> 2;    // node 0..67
    const int s   = tid & 3;     // K-chunk 0..3 (lanes 4j..4j+3 = node j)

    __shared__ __align__(16) float Ebuf[2][NPAD];

    const float tau_e = params[0], tau_i = params[1];
    const float P1 = params[2], P2 = params[3], P3 = params[4];
    const float P4 = params[5], P5 = params[6], Pp = params[7];
    const float kE = params[8], kI = params[9];
    const float LOG2E = 1.4426950408889634f;
    const float kE2 = -1.3f * LOG2E, bE2 = (1.3f * 4.0f) * LOG2E;
    const float kI2 = -2.0f * LOG2E, bI2 = (2.0f * 3.7f) * LOG2E;
    const float s0E = 1.0f / (1.0f + expf(5.2f));
    const float s0I = 1.0f / (1.0f + expf(7.4f));
    const float inv_te = 1.0f / tau_e, inv_ti = 1.0f / tau_i;

    // C chunk: 5 quads; global quad index g = 5s+qi valid iff < 17 (68/4).
    // Guarded loads (not post-masked) to avoid OOB on the last row.
    const float* crow = Cjk + j * NN + CH * s;
    const int g0 = 5 * s;
    const float4 z4 = make_float4(0.f, 0.f, 0.f, 0.f);
    float4 c0 = (g0 + 0 < 17) ? *(const float4*)(crow +  0) : z4;
    float4 c1 = (g0 + 1 < 17) ? *(const float4*)(crow +  4) : z4;
    float4 c2 = (g0 + 2 < 17) ? *(const float4*)(crow +  8) : z4;
    float4 c3 = (g0 + 3 < 17) ? *(const float4*)(crow + 12) : z4;
    float4 c4 = (g0 + 4 < 17) ? *(const float4*)(crow + 16) : z4;
    PIN4(c0); PIN4(c1); PIN4(c2); PIN4(c3); PIN4(c4);

    if (tid < 2 * NPAD) {
        const int b = tid / NPAD, k = tid - b * NPAD;
        Ebuf[b][k] = (b == 0 && k < NN) ? y0[k] : 0.0f;  // E_0 + persistent pad zeros
    }
    float E = y0[j];
    float I = y0[NN + j];
    asm volatile("s_waitcnt lgkmcnt(0)\ns_barrier" ::: "memory");

    // prologue: E_0 chunk into regs, conn_0 = C @ E_0
    const float* eb0 = &Ebuf[0][CH * s];
    float4 e0 = ((const float4*)eb0)[0], e1 = ((const float4*)eb0)[1],
           e2 = ((const float4*)eb0)[2], e3 = ((const float4*)eb0)[3],
           e4 = ((const float4*)eb0)[4];
    float conn;
    {
        float a0 = 0.f, a1 = 0.f, a2 = 0.f, a3 = 0.f;
        MAC4(c0, e0) MAC4(c1, e1) MAC4(c2, e2) MAC4(c3, e3) MAC4(c4, e4)
        float p = (a0 + a1) + (a2 + a3);
        p += dpp_xor1(p);
        conn = p + dpp_xor2(p);
    }

    float* op = out + (size_t)j * (size_t)num_steps;

    // One Euler step. Order is the pipeline: elem -> write E_{t+1} -> BAR ->
    // prefetch E_{t+1} (consumed NEXT step) -> MAC over E_t regs (prefetched
    // LAST step; LDS latency fully hidden by one compartment of slack).
#define STEP(BW, IDX)                                                         \
    {                                                                         \
        const float u  = fmaf(P1, E, fmaf(-P2, I, Pp));                       \
        const float vE = kE - E;                                              \
        const float wE = fmaf(vE, s0E, E);                                    \
        const float xI = fmaf(P3, E, -(P4 * I));                              \
        const float SI = FAST_RCP(1.0f + FAST_EXP2(fmaf(kI2, xI, bI2)));      \
        const float vI = kI - I;                                              \
        const float wI = fmaf(vI, s0I, I);                                    \
        const float In = fmaf(fmaf(vI, SI, -wI), inv_ti, I);                  \
        const float xE = fmaf(P5, conn, u);    /* conn-dep chain starts */    \
        const float SE = FAST_RCP(1.0f + FAST_EXP2(fmaf(kE2, xE, bE2)));      \
        const float En = fmaf(fmaf(vE, SE, -wE), inv_te, E);                  \
        if (s == 0) { Ebuf[BW][j] = En; op[IDX] = En - In; }                  \
        asm volatile("s_waitcnt lgkmcnt(0)\ns_barrier" ::: "memory");         \
        const float* ebp = &Ebuf[BW][CH * s];                                 \
        const float4 n0 = ((const float4*)ebp)[0], n1 = ((const float4*)ebp)[1], \
                     n2 = ((const float4*)ebp)[2], n3 = ((const float4*)ebp)[3], \
                     n4 = ((const float4*)ebp)[4];                            \
        float a0 = 0.f, a1 = 0.f, a2 = 0.f, a3 = 0.f;                         \
        MAC4(c0, e0) MAC4(c1, e1) MAC4(c2, e2) MAC4(c3, e3) MAC4(c4, e4)      \
        float p = (a0 + a1) + (a2 + a3);                                      \
        p += dpp_xor1(p);                                                     \
        conn = p + dpp_xor2(p);                                               \
        e0 = n0; e1 = n1; e2 = n2; e3 = n3; e4 = n4;                          \
        E = En; I = In;                                                       \
    }

    int t = 0;
    for (; t + 1 < num_steps; t += 2) {   // E_t lives in buf[t&1]
        STEP(1, t)
        STEP(0, t + 1)
    }
    if (t < num_steps) { STEP(1, t) }
#undef STEP
}

extern "C" void kernel_launch(void* const* d_in, const int* in_sizes, int n_in,
                              void* d_out, int out_size, void* d_ws, size_t ws_size,
                              hipStream_t stream) {
    const float* params = (const float*)d_in[0];
    const float* Cjk    = (const float*)d_in[1];
    const float* y0     = (const float*)d_in[2];
    const int num_steps = out_size / NN;

    nmm_kernel<<<dim3(1), dim3(NT), 0, stream>>>(
        params, Cjk, y0, (float*)d_out, num_steps);
}